// Round 17
// baseline (119.802 us; speedup 1.0000x reference)
//
#include <hip/hip_runtime.h>
#include <stdint.h>

typedef __attribute__((ext_vector_type(4))) float f32x4;
typedef __attribute__((ext_vector_type(8))) short s16x8;

static constexpr int S_TOK = 4096;   // B*T
static constexpr int CDIM  = 1024;
static constexpr int HDIM  = 1024;
static constexpr int H2    = 2048;
static constexpr int NEXP  = 8;

#define MAXRT2 40   // max routed 256-row tiles: 8192/256 + 8 partials

__device__ __forceinline__ unsigned short f2bf(float f) {
  union { float f; uint32_t u; } c; c.f = f;
  uint32_t u = c.u;
  u += 0x7fffu + ((u >> 16) & 1u);   // RNE
  return (unsigned short)(u >> 16);
}

__device__ __forceinline__ float bf2f(unsigned short u) {
  return __uint_as_float(((uint32_t)u) << 16);
}

__device__ __forceinline__ void gload16(const void* g, void* l) {
  __builtin_amdgcn_global_load_lds(
      (const __attribute__((address_space(1))) void*)g,
      (__attribute__((address_space(3))) void*)l, 16, 0, 0);
}

// ---------- router: fp32 logits, softmax, top-2. Fused x -> bf16 cast. (R15) ----------
__global__ void router_kernel(const float* __restrict__ x, const float* __restrict__ wg,
                              const float* __restrict__ gb,
                              int2* __restrict__ ti_e, float2* __restrict__ ti_w,
                              unsigned short* __restrict__ xb) {
  const int l = threadIdx.x & 63;
  const int wid = threadIdx.x >> 6;
  const int s = blockIdx.x * 4 + wid;
  const float* xr = x + (size_t)s * CDIM;
  unsigned short* xbr = xb + (size_t)s * CDIM;
  float acc[NEXP];
#pragma unroll
  for (int e = 0; e < NEXP; ++e) acc[e] = 0.f;
  for (int c = l; c < CDIM; c += 64) {
    float xv = xr[c];
    xbr[c] = f2bf(xv);                      // fused cast
    const float* wr_ = wg + (size_t)c * NEXP;
#pragma unroll
    for (int e = 0; e < NEXP; ++e) acc[e] += xv * wr_[e];
  }
#pragma unroll
  for (int e = 0; e < NEXP; ++e) {
#pragma unroll
    for (int off = 32; off > 0; off >>= 1) acc[e] += __shfl_xor(acc[e], off);
    acc[e] += gb[e];
  }
  float m = acc[0];
#pragma unroll
  for (int e = 1; e < NEXP; ++e) m = fmaxf(m, acc[e]);
  float ex[NEXP], sum = 0.f;
#pragma unroll
  for (int e = 0; e < NEXP; ++e) { ex[e] = __expf(acc[e] - m); sum += ex[e]; }
  int i0 = 0;
#pragma unroll
  for (int e = 1; e < NEXP; ++e) if (acc[e] > acc[i0]) i0 = e;  // lowest idx on tie
  int i1 = (i0 == 0) ? 1 : 0;
#pragma unroll
  for (int e = 0; e < NEXP; ++e) {
    if (e == i0) continue;
    if (acc[e] > acc[i1]) i1 = e;
  }
  if (l == 0) {
    const float inv = 1.f / sum;
    ti_e[s] = make_int2(i0, i1);
    ti_w[s] = make_float2(ex[i0] * inv, ex[i1] * inv);
  }
}

// ---------- prep + build fused: block 0 = gather build (256-thr), rest = weight prep ----------
// b==0: build. b in [1,4097): wprep w_in. [4097,5121): wso^T. [5121,13313): w2^T.
__global__ __launch_bounds__(256) void prep_build_kernel(
    const float* __restrict__ wsi, const float* __restrict__ w1s,
    const float* __restrict__ wso, const float* __restrict__ w2,
    unsigned short* __restrict__ w12i, unsigned short* __restrict__ wso_t,
    unsigned short* __restrict__ w2t,
    const int2* __restrict__ ti_e,
    int* __restrict__ cnt, int* __restrict__ offs,
    int* __restrict__ gidx, int2* __restrict__ ti_slot) {
  __shared__ float t[32][33];
  __shared__ int gcnt[64][NEXP];
  __shared__ int gbase[64][NEXP];
  __shared__ int eoff[NEXP];
  const int b = blockIdx.x;
  const int tid = threadIdx.x;

  if (b == 0) {
    // ---- deterministic counts/offsets/ranks/gather, 4 waves x 16 group-passes ----
    const int wid = tid >> 6, lane = tid & 63;
    for (int p = 0; p < 16; ++p) {
      const int g = p * 4 + wid;
      const int2 e = ti_e[g * 64 + lane];
#pragma unroll
      for (int ex = 0; ex < NEXP; ++ex) {
        uint64_t b0 = __ballot(e.x == ex);
        uint64_t b1 = __ballot(e.y == ex);
        if (lane == 0) gcnt[g][ex] = __popcll(b0) + __popcll(b1);
      }
    }
    __syncthreads();
    if (tid < NEXP) {
      const int ex = tid;
      int a = 0;
      for (int g = 0; g < 64; ++g) { gbase[g][ex] = a; a += gcnt[g][ex]; }
      eoff[ex] = a;
    }
    __syncthreads();
    if (tid == 0) {
      int a = 0;
#pragma unroll
      for (int ex = 0; ex < NEXP; ++ex) {
        const int c = eoff[ex];
        offs[ex] = a; cnt[ex] = c; eoff[ex] = a; a += c;
      }
      offs[NEXP] = a;
    }
    __syncthreads();
    for (int p = 0; p < 16; ++p) {
      const int g = p * 4 + wid;
      const int s = g * 64 + lane;
      const int2 e = ti_e[s];
      const uint64_t below = (lane == 0) ? 0ull : (~0ull >> (64 - lane));
      const uint64_t beloweq = below | (1ull << lane);
      int slot0 = 0, slot1 = 0;
#pragma unroll
      for (int ex = 0; ex < NEXP; ++ex) {
        uint64_t b0 = __ballot(e.x == ex);
        uint64_t b1 = __ballot(e.y == ex);
        const int base = gbase[g][ex];
        if (e.x == ex) slot0 = base + __popcll(b0 & below) + __popcll(b1 & below);
        if (e.y == ex) slot1 = base + __popcll(b0 & beloweq) + __popcll(b1 & below);
      }
      ti_slot[s] = make_int2(slot0, slot1);
      gidx[eoff[e.x] + slot0] = s;
      gidx[eoff[e.y] + slot1] = s;
    }
    return;
  }

  if (b < 4097) {                      // w_in prep: [C,2H] -> [4096,C] part-interleaved
    const int b2 = b - 1;
    const float* src = (b2 >= 2048) ? w1s : wsi;
    const int halfoff = (b2 >= 2048) ? 2048 : 0;
    const int rem = b2 & 2047;
    const int r0 = (rem >> 6) * 32;    // C dim
    const int c0 = (rem & 63) * 32;    // 2H dim
#pragma unroll
    for (int i = 0; i < 4; ++i) {
      int idx = tid + i * 256;
      int r = idx >> 5, c = idx & 31;
      t[r][c] = src[(size_t)(r0 + r) * H2 + c0 + c];
    }
    __syncthreads();
#pragma unroll
    for (int i = 0; i < 4; ++i) {
      int idx = tid + i * 256;
      int r = idx >> 5, c = idx & 31;
      const int ccol = c0 + r;
      const int part = ccol >> 10, h = ccol & 1023;
      const int drow = halfoff + (h & 15) + ((h >> 4) << 5) + (part << 4);
      w12i[(size_t)drow * CDIM + r0 + c] = f2bf(t[c][r]);
    }
    return;
  }
  // transpose+cast fp32 [1024,1024] -> bf16 transpose (wso, then 8x w2)
  const float* src;
  unsigned short* dst;
  int bx, by;
  if (b < 5121) {
    const int b3 = b - 4097;
    src = wso; dst = wso_t; by = b3 >> 5; bx = b3 & 31;
  } else {
    const int b4 = b - 5121;
    const int z = b4 >> 10;
    const int rem = b4 & 1023;
    src = w2 + (size_t)z * HDIM * CDIM;
    dst = w2t + (size_t)z * HDIM * CDIM;
    by = rem >> 5; bx = rem & 31;
  }
  const int r0 = by * 32, c0 = bx * 32;
#pragma unroll
  for (int i = 0; i < 4; ++i) {
    int idx = tid + i * 256;
    int r = idx >> 5, c = idx & 31;
    t[r][c] = src[(size_t)(r0 + r) * CDIM + c0 + c];
  }
  __syncthreads();
#pragma unroll
  for (int i = 0; i < 4; ++i) {
    int idx = tid + i * 256;
    int r = idx >> 5, c = idx & 31;
    dst[(size_t)(c0 + r) * HDIM + r0 + c] = f2bf(t[c][r]);
  }
}

// ============ shared depth-3 quad-buffer 256x256 core (R13/R15 pipeline) ============
__device__ __forceinline__ void core_d3(
    const unsigned short* pa0, const unsigned short* pa1,
    const unsigned short* pb0, const unsigned short* pb1,
    unsigned short* SA, unsigned short* SB,
    int tid, int wm, int wnh, int wno, int lr, int hi8,
    f32x4 (&acc)[8][4]) {
  const int t8 = tid * 8;
#pragma unroll
  for (int s = 0; s < 3; ++s) {
    const int kk = s * 32;
    gload16(pa0 + kk, SA + s * 8192 + t8);
    gload16(pa1 + kk, SA + s * 8192 + 4096 + t8);
    gload16(pb0 + kk, SB + s * 8192 + t8);
    gload16(pb1 + kk, SB + s * 8192 + 4096 + t8);
  }
  for (int s = 0; s < 32; ++s) {
    if (s < 30)       asm volatile("s_waitcnt vmcnt(8)" ::: "memory");
    else if (s == 30) asm volatile("s_waitcnt vmcnt(4)" ::: "memory");
    else              asm volatile("s_waitcnt vmcnt(0)" ::: "memory");
    __builtin_amdgcn_s_barrier();
    asm volatile("" ::: "memory");
    const int c = s & 3;
    const unsigned short* A_ = SA + c * 8192 + wm * 4096;
    const unsigned short* B_ = SB + c * 8192 + wnh * 4096;
    s16x8 a[8], b[4];
#pragma unroll
    for (int f = 0; f < 8; ++f) {
      const int r = f * 16 + lr;
      a[f] = *reinterpret_cast<const s16x8*>(&A_[r * 32 + (hi8 ^ (((r >> 1) & 3) << 3))]);
    }
#pragma unroll
    for (int j = 0; j < 4; ++j) {
      const int r = wno + j * 16 + lr;
      b[j] = *reinterpret_cast<const s16x8*>(&B_[r * 32 + (hi8 ^ (((r >> 1) & 3) << 3))]);
    }
    const int c3 = (s + 3) & 3;
    const int kk = (s + 3) * 32;
    const bool st = (s <= 28);
    if (st) gload16(pa0 + kk, SA + c3 * 8192 + t8);
    __builtin_amdgcn_s_setprio(1);
#pragma unroll
    for (int f = 0; f < 4; ++f) {
      acc[f][0] = __builtin_amdgcn_mfma_f32_16x16x32_bf16(a[f], b[0], acc[f][0], 0, 0, 0);
      acc[f][1] = __builtin_amdgcn_mfma_f32_16x16x32_bf16(a[f], b[1], acc[f][1], 0, 0, 0);
    }
    __builtin_amdgcn_s_setprio(0);
    if (st) gload16(pa1 + kk, SA + c3 * 8192 + 4096 + t8);
    __builtin_amdgcn_s_setprio(1);
#pragma unroll
    for (int f = 0; f < 4; ++f) {
      acc[f][2] = __builtin_amdgcn_mfma_f32_16x16x32_bf16(a[f], b[2], acc[f][2], 0, 0, 0);
      acc[f][3] = __builtin_amdgcn_mfma_f32_16x16x32_bf16(a[f], b[3], acc[f][3], 0, 0, 0);
    }
    __builtin_amdgcn_s_setprio(0);
    if (st) gload16(pb0 + kk, SB + c3 * 8192 + t8);
    __builtin_amdgcn_s_setprio(1);
#pragma unroll
    for (int f = 0; f < 4; ++f) {
      acc[4 + f][0] = __builtin_amdgcn_mfma_f32_16x16x32_bf16(a[4 + f], b[0], acc[4 + f][0], 0, 0, 0);
      acc[4 + f][1] = __builtin_amdgcn_mfma_f32_16x16x32_bf16(a[4 + f], b[1], acc[4 + f][1], 0, 0, 0);
    }
    __builtin_amdgcn_s_setprio(0);
    if (st) gload16(pb1 + kk, SB + c3 * 8192 + 4096 + t8);
    __builtin_amdgcn_s_setprio(1);
#pragma unroll
    for (int f = 0; f < 4; ++f) {
      acc[4 + f][2] = __builtin_amdgcn_mfma_f32_16x16x32_bf16(a[4 + f], b[2], acc[4 + f][2], 0, 0, 0);
      acc[4 + f][3] = __builtin_amdgcn_mfma_f32_16x16x32_bf16(a[4 + f], b[3], acc[4 + f][3], 0, 0, 0);
    }
    __builtin_amdgcn_s_setprio(0);
  }
}

// ---------- GEMM1: hid = swiglu(x @ [wsi|w1s]) fused -> Hs, Hr (depth-3 256²) ----------
__global__ __launch_bounds__(512) void gemm1_kernel(
    const unsigned short* __restrict__ xb, const unsigned short* __restrict__ w12i,
    unsigned short* __restrict__ Hs, unsigned short* __restrict__ Hr) {
  __shared__ unsigned short SA[4 * 2 * 4096];
  __shared__ unsigned short SB[4 * 2 * 4096];
  const int tid = threadIdx.x;
  const int l = tid & 63, wid = tid >> 6;
  const int wm = wid >> 2, wn = wid & 3;
  const int lr = l & 15;
  const int hi8 = (l >> 4) << 3;
  const int wnh = wn >> 1;
  const int wno = (wn & 1) << 6;
  // XCD swizzle: grid 16x16=256, chunk 32/XCD
  const int hw = blockIdx.y * gridDim.x + blockIdx.x;
  const int logical = (hw & 7) * 32 + (hw >> 3);
  const int m0 = (logical >> 4) * 256;
  const int n0 = (logical & 15) * 256;
  const int srow = tid >> 2;
  const int cs = (((tid & 3) ^ ((tid >> 3) & 3)) << 3);
  f32x4 acc[8][4] = {};
  const unsigned short* pa0 = xb + (size_t)(m0 + srow) * CDIM + cs;
  const unsigned short* pa1 = pa0 + (size_t)128 * CDIM;
  const unsigned short* pb0 = w12i + (size_t)(n0 + srow) * CDIM + cs;
  const unsigned short* pb1 = pb0 + (size_t)128 * CDIM;

  core_d3(pa0, pa1, pb0, pb1, SA, SB, tid, wm, wnh, wno, lr, hi8, acc);

  unsigned short* Hbuf = (n0 < 2048) ? Hs : Hr;
  const int rb = m0 + wm * 128 + ((l >> 4) << 2);
  const int hbase = ((n0 & 2047) >> 1) + wn * 32;
#pragma unroll
  for (int fm = 0; fm < 8; ++fm)
#pragma unroll
    for (int j = 0; j < 2; ++j)
#pragma unroll
      for (int r = 0; r < 4; ++r) {
        float av = acc[fm][2 * j][r];
        float bv = acc[fm][2 * j + 1][r];
        float hv = (av / (1.f + __expf(-av))) * bv;
        Hbuf[(size_t)(rb + fm * 16 + r) * HDIM + hbase + j * 16 + lr] = f2bf(hv);
      }
}

// ---------- GEMM2: depth-3 quad-buffer; dense shared-out (bf16 Dout) + ragged routed ----------
__global__ __launch_bounds__(512) void gemm2_kernel(
    const unsigned short* __restrict__ Hs, const unsigned short* __restrict__ Hr,
    const unsigned short* __restrict__ wso_t, const unsigned short* __restrict__ w2t,
    const int* __restrict__ cnt, const int* __restrict__ offs, const int* __restrict__ gidx,
    unsigned short* __restrict__ Dout, unsigned short* __restrict__ Eout) {
  __shared__ unsigned short SA[4 * 2 * 4096];
  __shared__ unsigned short SB[4 * 2 * 4096];
  const int tid = threadIdx.x;
  const int l = tid & 63, wid = tid >> 6;
  const int wm = wid >> 2, wn = wid & 3;
  const int lr = l & 15;
  const int hi8 = (l >> 4) << 3;
  const int wnh = wn >> 1;
  const int wno = (wn & 1) << 6;
  const int hw = blockIdx.y * gridDim.x + blockIdx.x;
  const int logical = (hw & 7) * 28 + (hw >> 3);
  const int gx = logical >> 2;
  const int n0 = (logical & 3) * 256;
  f32x4 acc[8][4] = {};

  const int srow = tid >> 2;
  const int cs = (((tid & 3) ^ ((tid >> 3) & 3)) << 3);

  const unsigned short *pa0, *pa1, *pb0, *pb1;
  int e = 0, cnte = 0, mt = 0, base = 0;
  const bool dense = (gx < 16);
  if (dense) {
    const int m0 = gx * 256;
    pa0 = Hs + (size_t)(m0 + srow) * HDIM + cs;
    pa1 = pa0 + (size_t)128 * HDIM;
    pb0 = wso_t + (size_t)(n0 + srow) * HDIM + cs;
    pb1 = pb0 + (size_t)128 * HDIM;
  } else {
    int t = gx - 16;
    bool found = false;
#pragma unroll
    for (int ee = 0; ee < NEXP; ++ee) {
      int c = cnt[ee];
      int nt = (c + 255) >> 8;
      if (!found) {
        if (t < nt) { e = ee; cnte = c; found = true; }
        else t -= nt;
      }
    }
    if (!found) return;
    mt = t;
    base = offs[e];
    const int r0 = mt * 256 + srow;
    const int tok0 = gidx[base + min(r0, cnte - 1)];
    const int tok1 = gidx[base + min(r0 + 128, cnte - 1)];
    pa0 = Hr + (size_t)tok0 * HDIM + cs;
    pa1 = Hr + (size_t)tok1 * HDIM + cs;
    pb0 = w2t + (size_t)e * CDIM * HDIM + (size_t)(n0 + srow) * HDIM + cs;
    pb1 = pb0 + (size_t)128 * HDIM;
  }

  core_d3(pa0, pa1, pb0, pb1, SA, SB, tid, wm, wnh, wno, lr, hi8, acc);

  const int rloc0 = wm * 128 + ((l >> 4) << 2);
  const int cb = n0 + wn * 64 + lr;
  if (dense) {
    const int rb = gx * 256 + rloc0;
#pragma unroll
    for (int fm = 0; fm < 8; ++fm)
#pragma unroll
      for (int fn = 0; fn < 4; ++fn)
#pragma unroll
        for (int r = 0; r < 4; ++r)
          Dout[(size_t)(rb + fm * 16 + r) * CDIM + cb + fn * 16] = f2bf(acc[fm][fn][r]);
  } else {
#pragma unroll
    for (int fm = 0; fm < 8; ++fm)
#pragma unroll
      for (int fn = 0; fn < 4; ++fn)
#pragma unroll
        for (int r = 0; r < 4; ++r) {
          const int rloc = mt * 256 + rloc0 + fm * 16 + r;
          if (rloc < cnte)
            Eout[(size_t)(base + rloc) * CDIM + cb + fn * 16] = f2bf(acc[fm][fn][r]);
        }
  }
}

// ---------- scatter: out[s] = Dout[s] + w0*Eout[p0] + w1*Eout[p1] (write-only out) ----------
__global__ void scatter_kernel(float* __restrict__ out, const unsigned short* __restrict__ Dout,
                               const unsigned short* __restrict__ Eout,
                               const int2* __restrict__ ti_e, const int2* __restrict__ ti_slot,
                               const float2* __restrict__ ti_w, const int* __restrict__ offs) {
  const int total = S_TOK * (CDIM / 8);
  int i = blockIdx.x * blockDim.x + threadIdx.x;
  const int st = gridDim.x * blockDim.x;
  for (; i < total; i += st) {
    const int s = i >> 7;
    const int j = (i & 127) << 3;
    const int2 e = ti_e[s];
    const int2 sl = ti_slot[s];
    const float2 wv = ti_w[s];
    const int p0 = offs[e.x] + sl.x;
    const int p1 = offs[e.y] + sl.y;
    const ushort4* d0 = reinterpret_cast<const ushort4*>(Dout + (size_t)s * CDIM + j);
    const ushort4* e0 = reinterpret_cast<const ushort4*>(Eout + (size_t)p0 * CDIM + j);
    const ushort4* e1 = reinterpret_cast<const ushort4*>(Eout + (size_t)p1 * CDIM + j);
    float* op = out + (size_t)s * CDIM + j;
#pragma unroll
    for (int q = 0; q < 2; ++q) {
      ushort4 dd = d0[q], a = e0[q], b = e1[q];
      float4 o;
      o.x = bf2f(dd.x) + wv.x * bf2f(a.x) + wv.y * bf2f(b.x);
      o.y = bf2f(dd.y) + wv.x * bf2f(a.y) + wv.y * bf2f(b.y);
      o.z = bf2f(dd.z) + wv.x * bf2f(a.z) + wv.y * bf2f(b.z);
      o.w = bf2f(dd.w) + wv.x * bf2f(a.w) + wv.y * bf2f(b.w);
      reinterpret_cast<float4*>(op)[q] = o;
    }
  }
}

extern "C" void kernel_launch(void* const* d_in, const int* in_sizes, int n_in,
                              void* d_out, int out_size, void* d_ws, size_t ws_size,
                              hipStream_t stream) {
  (void)in_sizes; (void)n_in; (void)out_size; (void)ws_size;
  const float* x   = (const float*)d_in[0];
  const float* wsi = (const float*)d_in[1];   // [C, 2H]
  const float* wso = (const float*)d_in[2];   // [H, C]
  const float* w1s = (const float*)d_in[3];   // [C, 2H]
  const float* w2  = (const float*)d_in[4];   // [E, H, C]
  const float* wg  = (const float*)d_in[5];   // [C, E]
  const float* gb  = (const float*)d_in[6];   // [E]
  float* out = (float*)d_out;

  char* w = (char*)d_ws;
  auto alloc = [&](size_t bytes) {
    char* p = w; w += (bytes + 255) & ~(size_t)255; return p;
  };
  unsigned short* xb    = (unsigned short*)alloc((size_t)S_TOK * CDIM * 2);
  unsigned short* w12i  = (unsigned short*)alloc((size_t)2 * H2 * CDIM * 2);
  unsigned short* wso_t = (unsigned short*)alloc((size_t)CDIM * HDIM * 2);
  unsigned short* w2t   = (unsigned short*)alloc((size_t)NEXP * CDIM * HDIM * 2);
  unsigned short* Hs    = (unsigned short*)alloc((size_t)S_TOK * HDIM * 2);
  unsigned short* Hr    = (unsigned short*)alloc((size_t)S_TOK * HDIM * 2);
  unsigned short* Dout  = (unsigned short*)alloc((size_t)S_TOK * CDIM * 2);
  unsigned short* Eout  = (unsigned short*)alloc((size_t)2 * S_TOK * CDIM * 2);
  int2*   ti_e   = (int2*)alloc((size_t)S_TOK * 8);
  int2*   ti_slot= (int2*)alloc((size_t)S_TOK * 8);
  float2* ti_w   = (float2*)alloc((size_t)S_TOK * 8);
  int*    cnt    = (int*)alloc(64);
  int*    offs   = (int*)alloc(64);
  int*    gidx   = (int*)alloc((size_t)2 * S_TOK * 4);

  // router (+ fused x->bf16 cast)
  router_kernel<<<S_TOK / 4, 256, 0, stream>>>(x, wg, gb, ti_e, ti_w, xb);

  // prep + build fused: block 0 builds gather lists, rest do weight prep
  prep_build_kernel<<<13313, 256, 0, stream>>>(
      wsi, w1s, wso, w2, w12i, wso_t, w2t, ti_e, cnt, offs, gidx, ti_slot);

  // stage 1: depth-3 quad-buffer 256², swiglu fused
  gemm1_kernel<<<dim3(16, 16), 512, 0, stream>>>(xb, w12i, Hs, Hr);

  // stage 2: depth-3 quad-buffer 256², dense shared-out (bf16) + ragged routed
  gemm2_kernel<<<dim3(16 + MAXRT2, CDIM / 256), 512, 0, stream>>>(
      Hs, Hr, wso_t, w2t, cnt, offs, gidx, Dout, Eout);

  // scatter: out = Dout + weighted expert contributions (write-only out)
  scatter_kernel<<<2048, 256, 0, stream>>>(out, Dout, Eout, ti_e, ti_slot, ti_w, offs);
}

// Round 18
// 113.960 us; speedup vs baseline: 1.0513x; 1.0513x over previous
//
#include <hip/hip_runtime.h>
#include <stdint.h>

typedef __attribute__((ext_vector_type(4))) float f32x4;
typedef __attribute__((ext_vector_type(8))) short s16x8;

static constexpr int S_TOK = 4096;   // B*T
static constexpr int CDIM  = 1024;
static constexpr int HDIM  = 1024;
static constexpr int H2    = 2048;
static constexpr int NEXP  = 8;

#define MAXRT2 40   // max routed 256-row tiles: 8192/256 + 8 partials

__device__ __forceinline__ unsigned short f2bf(float f) {
  union { float f; uint32_t u; } c; c.f = f;
  uint32_t u = c.u;
  u += 0x7fffu + ((u >> 16) & 1u);   // RNE
  return (unsigned short)(u >> 16);
}

__device__ __forceinline__ float bf2f(unsigned short u) {
  return __uint_as_float(((uint32_t)u) << 16);
}

__device__ __forceinline__ void gload16(const void* g, void* l) {
  __builtin_amdgcn_global_load_lds(
      (const __attribute__((address_space(1))) void*)g,
      (__attribute__((address_space(3))) void*)l, 16, 0, 0);
}

// ---------- fused prep (weights only): wprep w_in | transpose wso | transpose w2 ----------
// [0,4096) wprep, [4096,5120) wso transpose, [5120,13312) w2 transpose
__global__ __launch_bounds__(256) void prep_kernel(
    const float* __restrict__ wsi, const float* __restrict__ w1s,
    const float* __restrict__ wso, const float* __restrict__ w2,
    unsigned short* __restrict__ w12i, unsigned short* __restrict__ wso_t,
    unsigned short* __restrict__ w2t) {
  __shared__ float t[32][33];
  const int b = blockIdx.x;
  const int tid = threadIdx.x;

  if (b < 4096) {                      // w_in prep: [C,2H] -> [4096,C] part-interleaved
    const float* src = (b >= 2048) ? w1s : wsi;
    const int halfoff = (b >= 2048) ? 2048 : 0;
    const int rem = b & 2047;
    const int r0 = (rem >> 6) * 32;    // C dim
    const int c0 = (rem & 63) * 32;    // 2H dim
#pragma unroll
    for (int i = 0; i < 4; ++i) {
      int idx = tid + i * 256;
      int r = idx >> 5, c = idx & 31;
      t[r][c] = src[(size_t)(r0 + r) * H2 + c0 + c];
    }
    __syncthreads();
#pragma unroll
    for (int i = 0; i < 4; ++i) {
      int idx = tid + i * 256;
      int r = idx >> 5, c = idx & 31;
      const int ccol = c0 + r;
      const int part = ccol >> 10, h = ccol & 1023;
      const int drow = halfoff + (h & 15) + ((h >> 4) << 5) + (part << 4);
      w12i[(size_t)drow * CDIM + r0 + c] = f2bf(t[c][r]);
    }
    return;
  }
  // transpose+cast fp32 [1024,1024] -> bf16 transpose (wso, then 8x w2)
  const float* src;
  unsigned short* dst;
  int bx, by;
  if (b < 5120) {
    const int b3 = b - 4096;
    src = wso; dst = wso_t; by = b3 >> 5; bx = b3 & 31;
  } else {
    const int b4 = b - 5120;
    const int z = b4 >> 10;
    const int rem = b4 & 1023;
    src = w2 + (size_t)z * HDIM * CDIM;
    dst = w2t + (size_t)z * HDIM * CDIM;
    by = rem >> 5; bx = rem & 31;
  }
  const int r0 = by * 32, c0 = bx * 32;
#pragma unroll
  for (int i = 0; i < 4; ++i) {
    int idx = tid + i * 256;
    int r = idx >> 5, c = idx & 31;
    t[r][c] = src[(size_t)(r0 + r) * CDIM + c0 + c];
  }
  __syncthreads();
#pragma unroll
  for (int i = 0; i < 4; ++i) {
    int idx = tid + i * 256;
    int r = idx >> 5, c = idx & 31;
    dst[(size_t)(c0 + r) * HDIM + r0 + c] = f2bf(t[c][r]);
  }
}

// ---------- router: fp32 logits, softmax, top-2. Fused x -> bf16 cast. ----------
__global__ void router_kernel(const float* __restrict__ x, const float* __restrict__ wg,
                              const float* __restrict__ gb,
                              int2* __restrict__ ti_e, float2* __restrict__ ti_w,
                              unsigned short* __restrict__ xb) {
  const int l = threadIdx.x & 63;
  const int wid = threadIdx.x >> 6;
  const int s = blockIdx.x * 4 + wid;
  const float* xr = x + (size_t)s * CDIM;
  unsigned short* xbr = xb + (size_t)s * CDIM;
  float acc[NEXP];
#pragma unroll
  for (int e = 0; e < NEXP; ++e) acc[e] = 0.f;
  for (int c = l; c < CDIM; c += 64) {
    float xv = xr[c];
    xbr[c] = f2bf(xv);                      // fused cast
    const float* wr_ = wg + (size_t)c * NEXP;
#pragma unroll
    for (int e = 0; e < NEXP; ++e) acc[e] += xv * wr_[e];
  }
#pragma unroll
  for (int e = 0; e < NEXP; ++e) {
#pragma unroll
    for (int off = 32; off > 0; off >>= 1) acc[e] += __shfl_xor(acc[e], off);
    acc[e] += gb[e];
  }
  float m = acc[0];
#pragma unroll
  for (int e = 1; e < NEXP; ++e) m = fmaxf(m, acc[e]);
  float ex[NEXP], sum = 0.f;
#pragma unroll
  for (int e = 0; e < NEXP; ++e) { ex[e] = __expf(acc[e] - m); sum += ex[e]; }
  int i0 = 0;
#pragma unroll
  for (int e = 1; e < NEXP; ++e) if (acc[e] > acc[i0]) i0 = e;  // lowest idx on tie
  int i1 = (i0 == 0) ? 1 : 0;
#pragma unroll
  for (int e = 0; e < NEXP; ++e) {
    if (e == i0) continue;
    if (acc[e] > acc[i1]) i1 = e;
  }
  if (l == 0) {
    const float inv = 1.f / sum;
    ti_e[s] = make_int2(i0, i1);
    ti_w[s] = make_float2(ex[i0] * inv, ex[i1] * inv);
  }
}

// ---------- build: deterministic counts/offsets/ranks/gather via ballot scan ----------
__global__ __launch_bounds__(1024) void build_kernel(
    const int2* __restrict__ ti_e,
    int* __restrict__ cnt, int* __restrict__ offs,
    int* __restrict__ gidx, int2* __restrict__ ti_slot) {
  __shared__ int gcnt[64][NEXP];
  __shared__ int gbase[64][NEXP];
  __shared__ int eoff[NEXP];
  const int tid = threadIdx.x;
  const int wid = tid >> 6, lane = tid & 63;

  for (int p = 0; p < 4; ++p) {
    const int g = p * 16 + wid;
    const int2 e = ti_e[g * 64 + lane];
#pragma unroll
    for (int ex = 0; ex < NEXP; ++ex) {
      uint64_t b0 = __ballot(e.x == ex);
      uint64_t b1 = __ballot(e.y == ex);
      if (lane == 0) gcnt[g][ex] = __popcll(b0) + __popcll(b1);
    }
  }
  __syncthreads();
  if (tid < NEXP) {
    const int ex = tid;
    int a = 0;
    for (int g = 0; g < 64; ++g) { gbase[g][ex] = a; a += gcnt[g][ex]; }
    eoff[ex] = a;
  }
  __syncthreads();
  if (tid == 0) {
    int a = 0;
#pragma unroll
    for (int ex = 0; ex < NEXP; ++ex) {
      const int c = eoff[ex];
      offs[ex] = a; cnt[ex] = c; eoff[ex] = a; a += c;
    }
    offs[NEXP] = a;
  }
  __syncthreads();
  for (int p = 0; p < 4; ++p) {
    const int g = p * 16 + wid;
    const int s = g * 64 + lane;
    const int2 e = ti_e[s];
    const uint64_t below = (lane == 0) ? 0ull : (~0ull >> (64 - lane));
    const uint64_t beloweq = below | (1ull << lane);
    int slot0 = 0, slot1 = 0;
#pragma unroll
    for (int ex = 0; ex < NEXP; ++ex) {
      uint64_t b0 = __ballot(e.x == ex);
      uint64_t b1 = __ballot(e.y == ex);
      const int base = gbase[g][ex];
      if (e.x == ex) slot0 = base + __popcll(b0 & below) + __popcll(b1 & below);
      if (e.y == ex) slot1 = base + __popcll(b0 & beloweq) + __popcll(b1 & below);
    }
    ti_slot[s] = make_int2(slot0, slot1);
    gidx[eoff[e.x] + slot0] = s;
    gidx[eoff[e.y] + slot1] = s;
  }
}

// ============ shared depth-3 quad-buffer 256x256 core (R13/R15 pipeline) ============
__device__ __forceinline__ void core_d3(
    const unsigned short* pa0, const unsigned short* pa1,
    const unsigned short* pb0, const unsigned short* pb1,
    unsigned short* SA, unsigned short* SB,
    int tid, int wm, int wnh, int wno, int lr, int hi8,
    f32x4 (&acc)[8][4]) {
  const int t8 = tid * 8;
#pragma unroll
  for (int s = 0; s < 3; ++s) {
    const int kk = s * 32;
    gload16(pa0 + kk, SA + s * 8192 + t8);
    gload16(pa1 + kk, SA + s * 8192 + 4096 + t8);
    gload16(pb0 + kk, SB + s * 8192 + t8);
    gload16(pb1 + kk, SB + s * 8192 + 4096 + t8);
  }
  for (int s = 0; s < 32; ++s) {
    if (s < 30)       asm volatile("s_waitcnt vmcnt(8)" ::: "memory");
    else if (s == 30) asm volatile("s_waitcnt vmcnt(4)" ::: "memory");
    else              asm volatile("s_waitcnt vmcnt(0)" ::: "memory");
    __builtin_amdgcn_s_barrier();
    asm volatile("" ::: "memory");
    const int c = s & 3;
    const unsigned short* A_ = SA + c * 8192 + wm * 4096;
    const unsigned short* B_ = SB + c * 8192 + wnh * 4096;
    s16x8 a[8], b[4];
#pragma unroll
    for (int f = 0; f < 8; ++f) {
      const int r = f * 16 + lr;
      a[f] = *reinterpret_cast<const s16x8*>(&A_[r * 32 + (hi8 ^ (((r >> 1) & 3) << 3))]);
    }
#pragma unroll
    for (int j = 0; j < 4; ++j) {
      const int r = wno + j * 16 + lr;
      b[j] = *reinterpret_cast<const s16x8*>(&B_[r * 32 + (hi8 ^ (((r >> 1) & 3) << 3))]);
    }
    const int c3 = (s + 3) & 3;
    const int kk = (s + 3) * 32;
    const bool st = (s <= 28);
    if (st) gload16(pa0 + kk, SA + c3 * 8192 + t8);
    __builtin_amdgcn_s_setprio(1);
#pragma unroll
    for (int f = 0; f < 4; ++f) {
      acc[f][0] = __builtin_amdgcn_mfma_f32_16x16x32_bf16(a[f], b[0], acc[f][0], 0, 0, 0);
      acc[f][1] = __builtin_amdgcn_mfma_f32_16x16x32_bf16(a[f], b[1], acc[f][1], 0, 0, 0);
    }
    __builtin_amdgcn_s_setprio(0);
    if (st) gload16(pa1 + kk, SA + c3 * 8192 + 4096 + t8);
    __builtin_amdgcn_s_setprio(1);
#pragma unroll
    for (int f = 0; f < 4; ++f) {
      acc[f][2] = __builtin_amdgcn_mfma_f32_16x16x32_bf16(a[f], b[2], acc[f][2], 0, 0, 0);
      acc[f][3] = __builtin_amdgcn_mfma_f32_16x16x32_bf16(a[f], b[3], acc[f][3], 0, 0, 0);
    }
    __builtin_amdgcn_s_setprio(0);
    if (st) gload16(pb0 + kk, SB + c3 * 8192 + t8);
    __builtin_amdgcn_s_setprio(1);
#pragma unroll
    for (int f = 0; f < 4; ++f) {
      acc[4 + f][0] = __builtin_amdgcn_mfma_f32_16x16x32_bf16(a[4 + f], b[0], acc[4 + f][0], 0, 0, 0);
      acc[4 + f][1] = __builtin_amdgcn_mfma_f32_16x16x32_bf16(a[4 + f], b[1], acc[4 + f][1], 0, 0, 0);
    }
    __builtin_amdgcn_s_setprio(0);
    if (st) gload16(pb1 + kk, SB + c3 * 8192 + 4096 + t8);
    __builtin_amdgcn_s_setprio(1);
#pragma unroll
    for (int f = 0; f < 4; ++f) {
      acc[4 + f][2] = __builtin_amdgcn_mfma_f32_16x16x32_bf16(a[4 + f], b[2], acc[4 + f][2], 0, 0, 0);
      acc[4 + f][3] = __builtin_amdgcn_mfma_f32_16x16x32_bf16(a[4 + f], b[3], acc[4 + f][3], 0, 0, 0);
    }
    __builtin_amdgcn_s_setprio(0);
  }
}

// ---------- GEMM1: hid = swiglu(x @ [wsi|w1s]) fused -> Hs, Hr (depth-3 256²) ----------
__global__ __launch_bounds__(512) void gemm1_kernel(
    const unsigned short* __restrict__ xb, const unsigned short* __restrict__ w12i,
    unsigned short* __restrict__ Hs, unsigned short* __restrict__ Hr) {
  __shared__ unsigned short SA[4 * 2 * 4096];
  __shared__ unsigned short SB[4 * 2 * 4096];
  const int tid = threadIdx.x;
  const int l = tid & 63, wid = tid >> 6;
  const int wm = wid >> 2, wn = wid & 3;
  const int lr = l & 15;
  const int hi8 = (l >> 4) << 3;
  const int wnh = wn >> 1;
  const int wno = (wn & 1) << 6;
  // XCD swizzle: grid 16x16=256, chunk 32/XCD
  const int hw = blockIdx.y * gridDim.x + blockIdx.x;
  const int logical = (hw & 7) * 32 + (hw >> 3);
  const int m0 = (logical >> 4) * 256;
  const int n0 = (logical & 15) * 256;
  const int srow = tid >> 2;
  const int cs = (((tid & 3) ^ ((tid >> 3) & 3)) << 3);
  f32x4 acc[8][4] = {};
  const unsigned short* pa0 = xb + (size_t)(m0 + srow) * CDIM + cs;
  const unsigned short* pa1 = pa0 + (size_t)128 * CDIM;
  const unsigned short* pb0 = w12i + (size_t)(n0 + srow) * CDIM + cs;
  const unsigned short* pb1 = pb0 + (size_t)128 * CDIM;

  core_d3(pa0, pa1, pb0, pb1, SA, SB, tid, wm, wnh, wno, lr, hi8, acc);

  unsigned short* Hbuf = (n0 < 2048) ? Hs : Hr;
  const int rb = m0 + wm * 128 + ((l >> 4) << 2);
  const int hbase = ((n0 & 2047) >> 1) + wn * 32;
#pragma unroll
  for (int fm = 0; fm < 8; ++fm)
#pragma unroll
    for (int j = 0; j < 2; ++j)
#pragma unroll
      for (int r = 0; r < 4; ++r) {
        float av = acc[fm][2 * j][r];
        float bv = acc[fm][2 * j + 1][r];
        float hv = (av / (1.f + __expf(-av))) * bv;
        Hbuf[(size_t)(rb + fm * 16 + r) * HDIM + hbase + j * 16 + lr] = f2bf(hv);
      }
}

// ---------- GEMM2: depth-3 quad-buffer; dense shared-out (bf16 Dout) + ragged routed ----------
__global__ __launch_bounds__(512) void gemm2_kernel(
    const unsigned short* __restrict__ Hs, const unsigned short* __restrict__ Hr,
    const unsigned short* __restrict__ wso_t, const unsigned short* __restrict__ w2t,
    const int* __restrict__ cnt, const int* __restrict__ offs, const int* __restrict__ gidx,
    unsigned short* __restrict__ Dout, unsigned short* __restrict__ Eout) {
  __shared__ unsigned short SA[4 * 2 * 4096];
  __shared__ unsigned short SB[4 * 2 * 4096];
  const int tid = threadIdx.x;
  const int l = tid & 63, wid = tid >> 6;
  const int wm = wid >> 2, wn = wid & 3;
  const int lr = l & 15;
  const int hi8 = (l >> 4) << 3;
  const int wnh = wn >> 1;
  const int wno = (wn & 1) << 6;
  const int hw = blockIdx.y * gridDim.x + blockIdx.x;
  const int logical = (hw & 7) * 28 + (hw >> 3);
  const int gx = logical >> 2;
  const int n0 = (logical & 3) * 256;
  f32x4 acc[8][4] = {};

  const int srow = tid >> 2;
  const int cs = (((tid & 3) ^ ((tid >> 3) & 3)) << 3);

  const unsigned short *pa0, *pa1, *pb0, *pb1;
  int e = 0, cnte = 0, mt = 0, base = 0;
  const bool dense = (gx < 16);
  if (dense) {
    const int m0 = gx * 256;
    pa0 = Hs + (size_t)(m0 + srow) * HDIM + cs;
    pa1 = pa0 + (size_t)128 * HDIM;
    pb0 = wso_t + (size_t)(n0 + srow) * HDIM + cs;
    pb1 = pb0 + (size_t)128 * HDIM;
  } else {
    int t = gx - 16;
    bool found = false;
#pragma unroll
    for (int ee = 0; ee < NEXP; ++ee) {
      int c = cnt[ee];
      int nt = (c + 255) >> 8;
      if (!found) {
        if (t < nt) { e = ee; cnte = c; found = true; }
        else t -= nt;
      }
    }
    if (!found) return;
    mt = t;
    base = offs[e];
    const int r0 = mt * 256 + srow;
    const int tok0 = gidx[base + min(r0, cnte - 1)];
    const int tok1 = gidx[base + min(r0 + 128, cnte - 1)];
    pa0 = Hr + (size_t)tok0 * HDIM + cs;
    pa1 = Hr + (size_t)tok1 * HDIM + cs;
    pb0 = w2t + (size_t)e * CDIM * HDIM + (size_t)(n0 + srow) * HDIM + cs;
    pb1 = pb0 + (size_t)128 * HDIM;
  }

  core_d3(pa0, pa1, pb0, pb1, SA, SB, tid, wm, wnh, wno, lr, hi8, acc);

  const int rloc0 = wm * 128 + ((l >> 4) << 2);
  const int cb = n0 + wn * 64 + lr;
  if (dense) {
    const int rb = gx * 256 + rloc0;
#pragma unroll
    for (int fm = 0; fm < 8; ++fm)
#pragma unroll
      for (int fn = 0; fn < 4; ++fn)
#pragma unroll
        for (int r = 0; r < 4; ++r)
          Dout[(size_t)(rb + fm * 16 + r) * CDIM + cb + fn * 16] = f2bf(acc[fm][fn][r]);
  } else {
#pragma unroll
    for (int fm = 0; fm < 8; ++fm)
#pragma unroll
      for (int fn = 0; fn < 4; ++fn)
#pragma unroll
        for (int r = 0; r < 4; ++r) {
          const int rloc = mt * 256 + rloc0 + fm * 16 + r;
          if (rloc < cnte)
            Eout[(size_t)(base + rloc) * CDIM + cb + fn * 16] = f2bf(acc[fm][fn][r]);
        }
  }
}

// ---------- scatter: out[s] = Dout[s] + w0*Eout[p0] + w1*Eout[p1] (write-only out) ----------
__global__ void scatter_kernel(float* __restrict__ out, const unsigned short* __restrict__ Dout,
                               const unsigned short* __restrict__ Eout,
                               const int2* __restrict__ ti_e, const int2* __restrict__ ti_slot,
                               const float2* __restrict__ ti_w, const int* __restrict__ offs) {
  const int total = S_TOK * (CDIM / 8);
  int i = blockIdx.x * blockDim.x + threadIdx.x;
  const int st = gridDim.x * blockDim.x;
  for (; i < total; i += st) {
    const int s = i >> 7;
    const int j = (i & 127) << 3;
    const int2 e = ti_e[s];
    const int2 sl = ti_slot[s];
    const float2 wv = ti_w[s];
    const int p0 = offs[e.x] + sl.x;
    const int p1 = offs[e.y] + sl.y;
    const ushort4* d0 = reinterpret_cast<const ushort4*>(Dout + (size_t)s * CDIM + j);
    const ushort4* e0 = reinterpret_cast<const ushort4*>(Eout + (size_t)p0 * CDIM + j);
    const ushort4* e1 = reinterpret_cast<const ushort4*>(Eout + (size_t)p1 * CDIM + j);
    float* op = out + (size_t)s * CDIM + j;
#pragma unroll
    for (int q = 0; q < 2; ++q) {
      ushort4 dd = d0[q], a = e0[q], b = e1[q];
      float4 o;
      o.x = bf2f(dd.x) + wv.x * bf2f(a.x) + wv.y * bf2f(b.x);
      o.y = bf2f(dd.y) + wv.x * bf2f(a.y) + wv.y * bf2f(b.y);
      o.z = bf2f(dd.z) + wv.x * bf2f(a.z) + wv.y * bf2f(b.z);
      o.w = bf2f(dd.w) + wv.x * bf2f(a.w) + wv.y * bf2f(b.w);
      reinterpret_cast<float4*>(op)[q] = o;
    }
  }
}

extern "C" void kernel_launch(void* const* d_in, const int* in_sizes, int n_in,
                              void* d_out, int out_size, void* d_ws, size_t ws_size,
                              hipStream_t stream) {
  (void)in_sizes; (void)n_in; (void)out_size; (void)ws_size;
  const float* x   = (const float*)d_in[0];
  const float* wsi = (const float*)d_in[1];   // [C, 2H]
  const float* wso = (const float*)d_in[2];   // [H, C]
  const float* w1s = (const float*)d_in[3];   // [C, 2H]
  const float* w2  = (const float*)d_in[4];   // [E, H, C]
  const float* wg  = (const float*)d_in[5];   // [C, E]
  const float* gb  = (const float*)d_in[6];   // [E]
  float* out = (float*)d_out;

  char* w = (char*)d_ws;
  auto alloc = [&](size_t bytes) {
    char* p = w; w += (bytes + 255) & ~(size_t)255; return p;
  };
  unsigned short* xb    = (unsigned short*)alloc((size_t)S_TOK * CDIM * 2);
  unsigned short* w12i  = (unsigned short*)alloc((size_t)2 * H2 * CDIM * 2);
  unsigned short* wso_t = (unsigned short*)alloc((size_t)CDIM * HDIM * 2);
  unsigned short* w2t   = (unsigned short*)alloc((size_t)NEXP * CDIM * HDIM * 2);
  unsigned short* Hs    = (unsigned short*)alloc((size_t)S_TOK * HDIM * 2);
  unsigned short* Hr    = (unsigned short*)alloc((size_t)S_TOK * HDIM * 2);
  unsigned short* Dout  = (unsigned short*)alloc((size_t)S_TOK * CDIM * 2);
  unsigned short* Eout  = (unsigned short*)alloc((size_t)2 * S_TOK * CDIM * 2);
  int2*   ti_e   = (int2*)alloc((size_t)S_TOK * 8);
  int2*   ti_slot= (int2*)alloc((size_t)S_TOK * 8);
  float2* ti_w   = (float2*)alloc((size_t)S_TOK * 8);
  int*    cnt    = (int*)alloc(64);
  int*    offs   = (int*)alloc(64);
  int*    gidx   = (int*)alloc((size_t)2 * S_TOK * 4);

  // router (+ fused x->bf16 cast) + deterministic gather build
  router_kernel<<<S_TOK / 4, 256, 0, stream>>>(x, wg, gb, ti_e, ti_w, xb);
  build_kernel<<<1, 1024, 0, stream>>>(ti_e, cnt, offs, gidx, ti_slot);

  // fused prep (weights only): w_in interleave | wso^T | w2^T
  prep_kernel<<<13312, 256, 0, stream>>>(wsi, w1s, wso, w2, w12i, wso_t, w2t);

  // stage 1: depth-3 quad-buffer 256², swiglu fused
  gemm1_kernel<<<dim3(16, 16), 512, 0, stream>>>(xb, w12i, Hs, Hr);

  // stage 2: depth-3 quad-buffer 256², dense shared-out (bf16) + ragged routed
  gemm2_kernel<<<dim3(16 + MAXRT2, CDIM / 256), 512, 0, stream>>>(
      Hs, Hr, wso_t, w2t, cnt, offs, gidx, Dout, Eout);

  // scatter: out = Dout + weighted expert contributions (write-only out)
  scatter_kernel<<<2048, 256, 0, stream>>>(out, Dout, Eout, ti_e, ti_slot, ti_w, offs);
}